// Round 11
// baseline (39.707 us; speedup 1.0000x reference)
//
#include <hip/hip_runtime.h>
#include <math.h>

#define BATCH 16
#define HH 512
#define WW 512
#define PLANE ((size_t)HH * WW)
#define NELEM ((size_t)BATCH * 3 * PLANE)

// Quant divisor tables, reference's .T applied: QT[u][v] (small ints, exact f32)
__constant__ float QYT[8][8] = {
  {16,12,14,14,18,24,49,72},
  {11,12,13,17,22,35,64,92},
  {10,14,16,22,37,55,78,95},
  {16,19,24,29,56,64,87,98},
  {24,26,40,51,68,81,103,112},
  {40,58,57,87,109,104,121,100},
  {51,60,69,80,103,113,120,103},
  {61,55,56,62,77,92,101,99},
};
__constant__ float QCT[8][8] = {
  {17,18,24,47,99,99,99,99},
  {18,21,26,66,99,99,99,99},
  {24,26,56,99,99,99,99,99},
  {47,66,99,99,99,99,99,99},
  {99,99,99,99,99,99,99,99},
  {99,99,99,99,99,99,99,99},
  {99,99,99,99,99,99,99,99},
  {99,99,99,99,99,99,99,99},
};

// 32x64-pixel tile per 256-thread WG (4 waves). Grid = 2048 WGs = 8 WG/CU
// -> 32 waves/CU. Blocked LDS: Blk[bk][68]; 0..31 Y, 32..39 Cb, 40..47 Cr.
extern "C" __global__ __launch_bounds__(256, 8)
void diffjpeg_kernel(const float* __restrict__ x, const float* __restrict__ src,
                     float* __restrict__ out) {
  __shared__ float Blk[48][68];
  __shared__ float Cs[64];   // Cs[a*8+b] = f32 _COS[a][b] (numpy bit-match)

  const int blk = blockIdx.x;
  const int b   = blk >> 7;          // image 0..15
  const int t   = blk & 127;         // tile (16 rows x 8 cols of 32x64 tiles)
  const int trow = t >> 3, tcol = t & 7;
  const int row0 = trow * 32, col0 = tcol * 64;
  const int tid = threadIdx.x;

  // ---- phase 0: numpy-bitwise cos table ----
  if (tid < 64) {
    int a = tid >> 3, bb = tid & 7;
    float t2 = (float)((2 * a + 1) * bb);
    float t3 = __fmul_rn(t2, 3.14159265358979323846f);
    float t4 = __fmul_rn(t3, 0.0625f);
    Cs[tid] = (float)cos((double)t4);
  }

  const float* Rp = x + (size_t)(b * 3 + 0) * PLANE;
  const float* Gp = x + (size_t)(b * 3 + 1) * PLANE;
  const float* Bp = x + (size_t)(b * 3 + 2) * PLANE;

  const float4* s4 = (const float4*)src;
  float4*       d4 = (float4*)(out + NELEM);
  const size_t base4 = (size_t)blk * 1536;

  // ---- phase 1: thread owns 2 rows x 4 cols; float4 loads; YCC; 2x2 mean ----
  {
    int uy = tid >> 4, ux = tid & 15;       // 16 row-pairs x 16 col-quads
    size_t base = (size_t)(row0 + 2 * uy) * WW + (col0 + 4 * ux);
    float4 r0 = *(const float4*)(Rp + base);
    float4 r1 = *(const float4*)(Rp + base + WW);
    float4 g0 = *(const float4*)(Gp + base);
    float4 g1 = *(const float4*)(Gp + base + WW);
    float4 b0 = *(const float4*)(Bp + base);
    float4 b1 = *(const float4*)(Bp + base + WW);

    float rf[8] = {r0.x, r0.y, r1.x, r1.y,  r0.z, r0.w, r1.z, r1.w};
    float gf[8] = {g0.x, g0.y, g1.x, g1.y,  g0.z, g0.w, g1.z, g1.w};
    float bf[8] = {b0.x, b0.y, b1.x, b1.y,  b0.z, b0.w, b1.z, b1.w};
    float Ym[8], CB[8], CR[8];
    #pragma unroll
    for (int j = 0; j < 8; ++j) {
      float R  = __fmul_rn(rf[j], 255.0f);
      float G  = __fmul_rn(gf[j], 255.0f);
      float Bv = __fmul_rn(bf[j], 255.0f);
      float Yv = __fmaf_rn(Bv, 0.114f, __fmaf_rn(G, 0.587f, __fmul_rn(R, 0.299f)));
      Ym[j] = __fsub_rn(Yv, 128.0f);               // DCT input shift (moved)
      CB[j] = __fadd_rn(
          __fmaf_rn(Bv, 0.5f, __fmaf_rn(G, -0.331264f, __fmul_rn(R, -0.168736f))),
          128.0f);
      CR[j] = __fadd_rn(
          __fmaf_rn(Bv, -0.081312f, __fmaf_rn(G, -0.418688f, __fmul_rn(R, 0.5f))),
          128.0f);
    }

    int ybk = (uy >> 2) * 8 + (ux >> 1);
    int xin = (uy & 3) * 2, yin = (ux & 1) * 4;
    *(float4*)&Blk[ybk][xin * 8 + yin] =
        make_float4(Ym[0], Ym[1], Ym[4], Ym[5]);
    *(float4*)&Blk[ybk][(xin + 1) * 8 + yin] =
        make_float4(Ym[2], Ym[3], Ym[6], Ym[7]);

    float sb0 = __fadd_rn(__fadd_rn(__fadd_rn(CB[0], CB[1]), CB[2]), CB[3]);
    float sb1 = __fadd_rn(__fadd_rn(__fadd_rn(CB[4], CB[5]), CB[6]), CB[7]);
    float sr0 = __fadd_rn(__fadd_rn(__fadd_rn(CR[0], CR[1]), CR[2]), CR[3]);
    float sr1 = __fadd_rn(__fadd_rn(__fadd_rn(CR[4], CR[5]), CR[6]), CR[7]);
    int cbk = 32 + (uy >> 3) * 4 + (ux >> 2);
    int coff = (uy & 7) * 8 + ((2 * ux) & 7);
    *(float2*)&Blk[cbk][coff] = make_float2(
        __fsub_rn(__fmul_rn(sb0, 0.25f), 128.0f),
        __fsub_rn(__fmul_rn(sb1, 0.25f), 128.0f));
    *(float2*)&Blk[cbk + 8][coff] = make_float2(
        __fsub_rn(__fmul_rn(sr0, 0.25f), 128.0f),
        __fsub_rn(__fmul_rn(sr1, 0.25f), 128.0f));
  }
  __syncthreads();

  // ---- phase 4a: first half of source_image copy, issued at the top of the
  // barrier-free phase-2 region: HBM loads/stores drain under the FMA work.
  {
    #pragma unroll
    for (int i = 0; i < 3; ++i) {
      size_t f = base4 + i * 256 + tid;
      d4[f] = s4[f];
    }
  }

  // ---- phase 2: lane owns coefficient (u,v); wave owns 12 blocks ----
  const int w    = tid >> 6;
  const int lane = tid & 63;
  const int u = lane >> 3, v = lane & 7;
  const float au = (u == 0) ? 0.70710678118654746f : 1.0f;
  const float av = (v == 0) ? 0.70710678118654746f : 1.0f;
  const float ao  = __fmul_rn(au, av);        // ALPHA_OUTER[u][v]
  const float sc  = __fmul_rn(ao, 0.25f);     // SCALE[u][v]
  const float qdY = __fmul_rn(QYT[u][v], 0.4f);
  const float qdC = __fmul_rn(QCT[u][v], 0.4f);
  const int  bk0  = w * 12;

  // ---- 2a: non-separable DCT (bit-exact np chain) + quant + diff_round ----
  {
    float cuA[8], cvA[8];   // cuA[x]=Cs[x*8+u], cvA[y]=Cs[y*8+v]
    #pragma unroll
    for (int k = 0; k < 8; ++k) { cuA[k] = Cs[k * 8 + u]; cvA[k] = Cs[k * 8 + v]; }
    float acc[12];
    #pragma unroll
    for (int j = 0; j < 12; ++j) acc[j] = 0.f;
    #pragma unroll
    for (int ch = 0; ch < 4; ++ch) {
      float W[16];
      #pragma unroll
      for (int xy = 0; xy < 16; ++xy) {
        int k = ch * 16 + xy;
        W[xy] = __fmul_rn(cuA[k >> 3], cvA[k & 7]);   // f32 DCT_T entry
      }
      #pragma unroll
      for (int j = 0; j < 12; ++j) {
        const float* A = Blk[bk0 + j] + ch * 16;      // wave-uniform broadcast
        float4 a0 = *(const float4*)(A);
        float4 a1 = *(const float4*)(A + 4);
        float4 a2 = *(const float4*)(A + 8);
        float4 a3 = *(const float4*)(A + 12);
        float s = acc[j];
        s = __fmaf_rn(a0.x, W[ 0], s); s = __fmaf_rn(a0.y, W[ 1], s);
        s = __fmaf_rn(a0.z, W[ 2], s); s = __fmaf_rn(a0.w, W[ 3], s);
        s = __fmaf_rn(a1.x, W[ 4], s); s = __fmaf_rn(a1.y, W[ 5], s);
        s = __fmaf_rn(a1.z, W[ 6], s); s = __fmaf_rn(a1.w, W[ 7], s);
        s = __fmaf_rn(a2.x, W[ 8], s); s = __fmaf_rn(a2.y, W[ 9], s);
        s = __fmaf_rn(a2.z, W[10], s); s = __fmaf_rn(a2.w, W[11], s);
        s = __fmaf_rn(a3.x, W[12], s); s = __fmaf_rn(a3.y, W[13], s);
        s = __fmaf_rn(a3.w, W[15], __fmaf_rn(a3.z, W[14], s));
        acc[j] = s;
      }
    }
    #pragma unroll
    for (int j = 0; j < 12; ++j) {
      int bk = bk0 + j;
      float qd = (bk < 32) ? qdY : qdC;
      float Sp = __fmul_rn(sc, acc[j]);
      float qv = __fdiv_rn(Sp, qd);
      float r  = rintf(qv);
      float dd = __fsub_rn(qv, r);
      float e  = __fadd_rn(r, __fmul_rn(__fmul_rn(dd, dd), dd));
      Blk[bk][lane] = __fmul_rn(__fmul_rn(e, qd), ao);   // e at [u*8+v]
    }
  }

  // ---- 2b: SEPARABLE IDCT (post-round: numerically free to reorder) ----
  {
    float cuB[8], cvB[8];  // cuB[k]=Cs[u*8+k], cvB[k]=Cs[v*8+k]
    #pragma unroll
    for (int k = 0; k < 8; ++k) { cuB[k] = Cs[u * 8 + k]; cvB[k] = Cs[v * 8 + k]; }

    // pass A (2 blocks per iter; wave-lockstep: reads precede in-place writes)
    #pragma unroll
    for (int pb = 0; pb < 6; ++pb) {
      int bkA = bk0 + 2 * pb, bkB = bkA + 1;
      const float* A = Blk[bkA] + u * 8;   // own row x=u (32B contiguous)
      const float* C = Blk[bkB] + u * 8;
      float4 a0 = *(const float4*)(A);
      float4 a1 = *(const float4*)(A + 4);
      float4 c0 = *(const float4*)(C);
      float4 c1 = *(const float4*)(C + 4);
      float sA = __fmul_rn(a0.x, cvB[0]);
      float sB = __fmul_rn(c0.x, cvB[0]);
      sA = __fmaf_rn(a0.y, cvB[1], sA); sB = __fmaf_rn(c0.y, cvB[1], sB);
      sA = __fmaf_rn(a0.z, cvB[2], sA); sB = __fmaf_rn(c0.z, cvB[2], sB);
      sA = __fmaf_rn(a0.w, cvB[3], sA); sB = __fmaf_rn(c0.w, cvB[3], sB);
      sA = __fmaf_rn(a1.x, cvB[4], sA); sB = __fmaf_rn(c1.x, cvB[4], sB);
      sA = __fmaf_rn(a1.y, cvB[5], sA); sB = __fmaf_rn(c1.y, cvB[5], sB);
      sA = __fmaf_rn(a1.z, cvB[6], sA); sB = __fmaf_rn(c1.z, cvB[6], sB);
      sA = __fmaf_rn(a1.w, cvB[7], sA); sB = __fmaf_rn(c1.w, cvB[7], sB);
      Blk[bkA][v * 8 + u] = sA;            // transposed store (2-way banks)
      Blk[bkB][v * 8 + u] = sB;
    }

    // pass B
    #pragma unroll
    for (int pb = 0; pb < 6; ++pb) {
      int bkA = bk0 + 2 * pb, bkB = bkA + 1;
      const float* A = Blk[bkA] + v * 8;   // row v holds T[x][v], x contiguous
      const float* C = Blk[bkB] + v * 8;
      float4 a0 = *(const float4*)(A);
      float4 a1 = *(const float4*)(A + 4);
      float4 c0 = *(const float4*)(C);
      float4 c1 = *(const float4*)(C + 4);
      float sA = __fmul_rn(a0.x, cuB[0]);
      float sB = __fmul_rn(c0.x, cuB[0]);
      sA = __fmaf_rn(a0.y, cuB[1], sA); sB = __fmaf_rn(c0.y, cuB[1], sB);
      sA = __fmaf_rn(a0.z, cuB[2], sA); sB = __fmaf_rn(c0.z, cuB[2], sB);
      sA = __fmaf_rn(a0.w, cuB[3], sA); sB = __fmaf_rn(c0.w, cuB[3], sB);
      sA = __fmaf_rn(a1.x, cuB[4], sA); sB = __fmaf_rn(c1.x, cuB[4], sB);
      sA = __fmaf_rn(a1.y, cuB[5], sA); sB = __fmaf_rn(c1.y, cuB[5], sB);
      sA = __fmaf_rn(a1.z, cuB[6], sA); sB = __fmaf_rn(c1.z, cuB[6], sB);
      sA = __fmaf_rn(a1.w, cuB[7], sA); sB = __fmaf_rn(c1.w, cuB[7], sB);
      Blk[bkA][lane] = __fadd_rn(__fmul_rn(0.25f, sA), 128.0f);  // [u*8+v]
      Blk[bkB][lane] = __fadd_rn(__fmul_rn(0.25f, sB), 128.0f);
    }
  }

  // ---- phase 4b: second half of source_image copy ----
  {
    #pragma unroll
    for (int i = 3; i < 6; ++i) {
      size_t f = base4 + i * 256 + tid;
      d4[f] = s4[f];
    }
  }
  __syncthreads();

  // ---- phase 3: upsample, -128, sgemm-FMA YCC->RGB, clip, /255, store ----
  float* oR = out + (size_t)(b * 3 + 0) * PLANE;
  float* oG = out + (size_t)(b * 3 + 1) * PLANE;
  float* oB = out + (size_t)(b * 3 + 2) * PLANE;
  #pragma unroll
  for (int i = 0; i < 2; ++i) {
    int g = tid + i * 256;           // 32 rows x 16 groups of 4 px
    int py = g >> 4, pxg = g & 15;
    int col = pxg * 4;
    int ybk = (py >> 3) * 8 + (col >> 3);
    int yoff = (py & 7) * 8 + (col & 7);
    float4 yv4 = *(const float4*)&Blk[ybk][yoff];
    float yv[4] = {yv4.x, yv4.y, yv4.z, yv4.w};

    int cy = py >> 1, cx = 2 * pxg;
    int cbk = 32 + (cy >> 3) * 4 + (cx >> 3);
    int coff = (cy & 7) * 8 + (cx & 7);
    float2 cbv = *(const float2*)&Blk[cbk][coff];
    float2 crv = *(const float2*)&Blk[cbk + 8][coff];
    float cb0 = __fadd_rn(cbv.x, -128.0f);
    float cb1 = __fadd_rn(cbv.y, -128.0f);
    float cr0 = __fadd_rn(crv.x, -128.0f);
    float cr1 = __fadd_rn(crv.y, -128.0f);
    float cb[4] = {cb0, cb0, cb1, cb1};
    float cr[4] = {cr0, cr0, cr1, cr1};

    float rr[4], gg[4], bb[4];
    #pragma unroll
    for (int j = 0; j < 4; ++j) {
      float R  = __fmaf_rn(cr[j], 1.402f, yv[j]);
      float G  = __fmaf_rn(cr[j], -0.714136f, __fmaf_rn(cb[j], -0.344136f, yv[j]));
      float Bv = __fmaf_rn(cb[j], 1.772f, yv[j]);
      R  = fminf(fmaxf(R,  0.0f), 255.0f);
      G  = fminf(fmaxf(G,  0.0f), 255.0f);
      Bv = fminf(fmaxf(Bv, 0.0f), 255.0f);
      rr[j] = __fdiv_rn(R,  255.0f);
      gg[j] = __fdiv_rn(G,  255.0f);
      bb[j] = __fdiv_rn(Bv, 255.0f);
    }
    size_t o = (size_t)(row0 + py) * WW + (col0 + col);
    *(float4*)(oR + o) = make_float4(rr[0], rr[1], rr[2], rr[3]);
    *(float4*)(oG + o) = make_float4(gg[0], gg[1], gg[2], gg[3]);
    *(float4*)(oB + o) = make_float4(bb[0], bb[1], bb[2], bb[3]);
  }
}

extern "C" void kernel_launch(void* const* d_in, const int* in_sizes, int n_in,
                              void* d_out, int out_size, void* d_ws, size_t ws_size,
                              hipStream_t stream) {
  (void)in_sizes; (void)n_in; (void)d_ws; (void)ws_size; (void)out_size;
  const float* x   = (const float*)d_in[0];
  const float* src = (const float*)d_in[1];
  float* out = (float*)d_out;

  diffjpeg_kernel<<<dim3(BATCH * 128), dim3(256), 0, stream>>>(x, src, out);
}

// Round 12
// 38.312 us; speedup vs baseline: 1.0364x; 1.0364x over previous
//
#include <hip/hip_runtime.h>
#include <math.h>

#define BATCH 16
#define HH 512
#define WW 512
#define PLANE ((size_t)HH * WW)
#define NELEM ((size_t)BATCH * 3 * PLANE)

// Quant divisor tables, reference's .T applied: QT[u][v] (small ints, exact f32)
__constant__ float QYT[8][8] = {
  {16,12,14,14,18,24,49,72},
  {11,12,13,17,22,35,64,92},
  {10,14,16,22,37,55,78,95},
  {16,19,24,29,56,64,87,98},
  {24,26,40,51,68,81,103,112},
  {40,58,57,87,109,104,121,100},
  {51,60,69,80,103,113,120,103},
  {61,55,56,62,77,92,101,99},
};
__constant__ float QCT[8][8] = {
  {17,18,24,47,99,99,99,99},
  {18,21,26,66,99,99,99,99},
  {24,26,56,99,99,99,99,99},
  {47,66,99,99,99,99,99,99},
  {99,99,99,99,99,99,99,99},
  {99,99,99,99,99,99,99,99},
  {99,99,99,99,99,99,99,99},
  {99,99,99,99,99,99,99,99},
};

// f32(1/255): post-round multiply; |x*RCP255 - x/255| <= 2e-6 on [0,255],
// far under the 4.7e-4 absmax margin. (Pre-round divides stay exact.)
#define RCP255 3.92156862745098039e-03f

// 32x64-pixel tile per 256-thread WG (4 waves). Grid = 2048 WGs = 8 WG/CU
// -> 32 waves/CU. Blocked LDS: Blk[bk][68]; 0..31 Y, 32..39 Cb, 40..47 Cr.
extern "C" __global__ __launch_bounds__(256, 8)
void diffjpeg_kernel(const float* __restrict__ x, const float* __restrict__ src,
                     float* __restrict__ out) {
  __shared__ float Blk[48][68];
  __shared__ float Cs[64];   // Cs[a*8+b] = f32 _COS[a][b] (numpy bit-match)

  const int blk = blockIdx.x;
  const int b   = blk >> 7;          // image 0..15
  const int t   = blk & 127;         // tile (16 rows x 8 cols of 32x64 tiles)
  const int trow = t >> 3, tcol = t & 7;
  const int row0 = trow * 32, col0 = tcol * 64;
  const int tid = threadIdx.x;

  // ---- phase 0: numpy-bitwise cos table ----
  if (tid < 64) {
    int a = tid >> 3, bb = tid & 7;
    float t2 = (float)((2 * a + 1) * bb);
    float t3 = __fmul_rn(t2, 3.14159265358979323846f);
    float t4 = __fmul_rn(t3, 0.0625f);
    Cs[tid] = (float)cos((double)t4);
  }

  const float* Rp = x + (size_t)(b * 3 + 0) * PLANE;
  const float* Gp = x + (size_t)(b * 3 + 1) * PLANE;
  const float* Bp = x + (size_t)(b * 3 + 2) * PLANE;

  // ---- phase 1: thread owns 2 rows x 4 cols; float4 loads; YCC; 2x2 mean ----
  {
    int uy = tid >> 4, ux = tid & 15;       // 16 row-pairs x 16 col-quads
    size_t base = (size_t)(row0 + 2 * uy) * WW + (col0 + 4 * ux);
    float4 r0 = *(const float4*)(Rp + base);
    float4 r1 = *(const float4*)(Rp + base + WW);
    float4 g0 = *(const float4*)(Gp + base);
    float4 g1 = *(const float4*)(Gp + base + WW);
    float4 b0 = *(const float4*)(Bp + base);
    float4 b1 = *(const float4*)(Bp + base + WW);

    float rf[8] = {r0.x, r0.y, r1.x, r1.y,  r0.z, r0.w, r1.z, r1.w};
    float gf[8] = {g0.x, g0.y, g1.x, g1.y,  g0.z, g0.w, g1.z, g1.w};
    float bf[8] = {b0.x, b0.y, b1.x, b1.y,  b0.z, b0.w, b1.z, b1.w};
    float Ym[8], CB[8], CR[8];
    #pragma unroll
    for (int j = 0; j < 8; ++j) {
      float R  = __fmul_rn(rf[j], 255.0f);
      float G  = __fmul_rn(gf[j], 255.0f);
      float Bv = __fmul_rn(bf[j], 255.0f);
      float Yv = __fmaf_rn(Bv, 0.114f, __fmaf_rn(G, 0.587f, __fmul_rn(R, 0.299f)));
      Ym[j] = __fsub_rn(Yv, 128.0f);               // DCT input shift (moved)
      CB[j] = __fadd_rn(
          __fmaf_rn(Bv, 0.5f, __fmaf_rn(G, -0.331264f, __fmul_rn(R, -0.168736f))),
          128.0f);
      CR[j] = __fadd_rn(
          __fmaf_rn(Bv, -0.081312f, __fmaf_rn(G, -0.418688f, __fmul_rn(R, 0.5f))),
          128.0f);
    }

    int ybk = (uy >> 2) * 8 + (ux >> 1);
    int xin = (uy & 3) * 2, yin = (ux & 1) * 4;
    *(float4*)&Blk[ybk][xin * 8 + yin] =
        make_float4(Ym[0], Ym[1], Ym[4], Ym[5]);
    *(float4*)&Blk[ybk][(xin + 1) * 8 + yin] =
        make_float4(Ym[2], Ym[3], Ym[6], Ym[7]);

    float sb0 = __fadd_rn(__fadd_rn(__fadd_rn(CB[0], CB[1]), CB[2]), CB[3]);
    float sb1 = __fadd_rn(__fadd_rn(__fadd_rn(CB[4], CB[5]), CB[6]), CB[7]);
    float sr0 = __fadd_rn(__fadd_rn(__fadd_rn(CR[0], CR[1]), CR[2]), CR[3]);
    float sr1 = __fadd_rn(__fadd_rn(__fadd_rn(CR[4], CR[5]), CR[6]), CR[7]);
    int cbk = 32 + (uy >> 3) * 4 + (ux >> 2);
    int coff = (uy & 7) * 8 + ((2 * ux) & 7);
    *(float2*)&Blk[cbk][coff] = make_float2(
        __fsub_rn(__fmul_rn(sb0, 0.25f), 128.0f),
        __fsub_rn(__fmul_rn(sb1, 0.25f), 128.0f));
    *(float2*)&Blk[cbk + 8][coff] = make_float2(
        __fsub_rn(__fmul_rn(sr0, 0.25f), 128.0f),
        __fsub_rn(__fmul_rn(sr1, 0.25f), 128.0f));
  }
  __syncthreads();

  // ---- phase 2: lane owns coefficient (u,v); wave owns 12 blocks ----
  const int w    = tid >> 6;
  const int lane = tid & 63;
  const int u = lane >> 3, v = lane & 7;
  const float au = (u == 0) ? 0.70710678118654746f : 1.0f;
  const float av = (v == 0) ? 0.70710678118654746f : 1.0f;
  const float ao  = __fmul_rn(au, av);        // ALPHA_OUTER[u][v]
  const float sc  = __fmul_rn(ao, 0.25f);     // SCALE[u][v]
  const float qdY = __fmul_rn(QYT[u][v], 0.4f);
  const float qdC = __fmul_rn(QCT[u][v], 0.4f);
  const int  bk0  = w * 12;

  // ---- 2a: non-separable DCT (bit-exact np chain) + quant + diff_round ----
  {
    float cuA[8], cvA[8];   // cuA[x]=Cs[x*8+u], cvA[y]=Cs[y*8+v]
    #pragma unroll
    for (int k = 0; k < 8; ++k) { cuA[k] = Cs[k * 8 + u]; cvA[k] = Cs[k * 8 + v]; }
    float acc[12];
    #pragma unroll
    for (int j = 0; j < 12; ++j) acc[j] = 0.f;
    #pragma unroll
    for (int ch = 0; ch < 4; ++ch) {
      float W[16];
      #pragma unroll
      for (int xy = 0; xy < 16; ++xy) {
        int k = ch * 16 + xy;
        W[xy] = __fmul_rn(cuA[k >> 3], cvA[k & 7]);   // f32 DCT_T entry
      }
      #pragma unroll
      for (int j = 0; j < 12; ++j) {
        const float* A = Blk[bk0 + j] + ch * 16;      // wave-uniform broadcast
        float4 a0 = *(const float4*)(A);
        float4 a1 = *(const float4*)(A + 4);
        float4 a2 = *(const float4*)(A + 8);
        float4 a3 = *(const float4*)(A + 12);
        float s = acc[j];
        s = __fmaf_rn(a0.x, W[ 0], s); s = __fmaf_rn(a0.y, W[ 1], s);
        s = __fmaf_rn(a0.z, W[ 2], s); s = __fmaf_rn(a0.w, W[ 3], s);
        s = __fmaf_rn(a1.x, W[ 4], s); s = __fmaf_rn(a1.y, W[ 5], s);
        s = __fmaf_rn(a1.z, W[ 6], s); s = __fmaf_rn(a1.w, W[ 7], s);
        s = __fmaf_rn(a2.x, W[ 8], s); s = __fmaf_rn(a2.y, W[ 9], s);
        s = __fmaf_rn(a2.z, W[10], s); s = __fmaf_rn(a2.w, W[11], s);
        s = __fmaf_rn(a3.x, W[12], s); s = __fmaf_rn(a3.y, W[13], s);
        s = __fmaf_rn(a3.w, W[15], __fmaf_rn(a3.z, W[14], s));
        acc[j] = s;
      }
    }
    #pragma unroll
    for (int j = 0; j < 12; ++j) {
      int bk = bk0 + j;
      float qd = (bk < 32) ? qdY : qdC;
      float Sp = __fmul_rn(sc, acc[j]);
      float qv = __fdiv_rn(Sp, qd);                 // exact div: feeds rintf
      float r  = rintf(qv);
      float dd = __fsub_rn(qv, r);
      float e  = __fadd_rn(r, __fmul_rn(__fmul_rn(dd, dd), dd));
      Blk[bk][lane] = __fmul_rn(__fmul_rn(e, qd), ao);   // e at [u*8+v]
    }
  }

  // ---- 2b: SEPARABLE IDCT (post-round: numerically free to reorder) ----
  {
    float cuB[8], cvB[8];  // cuB[k]=Cs[u*8+k], cvB[k]=Cs[v*8+k]
    #pragma unroll
    for (int k = 0; k < 8; ++k) { cuB[k] = Cs[u * 8 + k]; cvB[k] = Cs[v * 8 + k]; }

    // pass A (2 blocks per iter; wave-lockstep: reads precede in-place writes)
    #pragma unroll
    for (int pb = 0; pb < 6; ++pb) {
      int bkA = bk0 + 2 * pb, bkB = bkA + 1;
      const float* A = Blk[bkA] + u * 8;   // own row x=u (32B contiguous)
      const float* C = Blk[bkB] + u * 8;
      float4 a0 = *(const float4*)(A);
      float4 a1 = *(const float4*)(A + 4);
      float4 c0 = *(const float4*)(C);
      float4 c1 = *(const float4*)(C + 4);
      float sA = __fmul_rn(a0.x, cvB[0]);
      float sB = __fmul_rn(c0.x, cvB[0]);
      sA = __fmaf_rn(a0.y, cvB[1], sA); sB = __fmaf_rn(c0.y, cvB[1], sB);
      sA = __fmaf_rn(a0.z, cvB[2], sA); sB = __fmaf_rn(c0.z, cvB[2], sB);
      sA = __fmaf_rn(a0.w, cvB[3], sA); sB = __fmaf_rn(c0.w, cvB[3], sB);
      sA = __fmaf_rn(a1.x, cvB[4], sA); sB = __fmaf_rn(c1.x, cvB[4], sB);
      sA = __fmaf_rn(a1.y, cvB[5], sA); sB = __fmaf_rn(c1.y, cvB[5], sB);
      sA = __fmaf_rn(a1.z, cvB[6], sA); sB = __fmaf_rn(c1.z, cvB[6], sB);
      sA = __fmaf_rn(a1.w, cvB[7], sA); sB = __fmaf_rn(c1.w, cvB[7], sB);
      Blk[bkA][v * 8 + u] = sA;            // transposed store (2-way banks)
      Blk[bkB][v * 8 + u] = sB;
    }

    // pass B
    #pragma unroll
    for (int pb = 0; pb < 6; ++pb) {
      int bkA = bk0 + 2 * pb, bkB = bkA + 1;
      const float* A = Blk[bkA] + v * 8;   // row v holds T[x][v], x contiguous
      const float* C = Blk[bkB] + v * 8;
      float4 a0 = *(const float4*)(A);
      float4 a1 = *(const float4*)(A + 4);
      float4 c0 = *(const float4*)(C);
      float4 c1 = *(const float4*)(C + 4);
      float sA = __fmul_rn(a0.x, cuB[0]);
      float sB = __fmul_rn(c0.x, cuB[0]);
      sA = __fmaf_rn(a0.y, cuB[1], sA); sB = __fmaf_rn(c0.y, cuB[1], sB);
      sA = __fmaf_rn(a0.z, cuB[2], sA); sB = __fmaf_rn(c0.z, cuB[2], sB);
      sA = __fmaf_rn(a0.w, cuB[3], sA); sB = __fmaf_rn(c0.w, cuB[3], sB);
      sA = __fmaf_rn(a1.x, cuB[4], sA); sB = __fmaf_rn(c1.x, cuB[4], sB);
      sA = __fmaf_rn(a1.y, cuB[5], sA); sB = __fmaf_rn(c1.y, cuB[5], sB);
      sA = __fmaf_rn(a1.z, cuB[6], sA); sB = __fmaf_rn(c1.z, cuB[6], sB);
      sA = __fmaf_rn(a1.w, cuB[7], sA); sB = __fmaf_rn(c1.w, cuB[7], sB);
      Blk[bkA][lane] = __fadd_rn(__fmul_rn(0.25f, sA), 128.0f);  // [u*8+v]
      Blk[bkB][lane] = __fadd_rn(__fmul_rn(0.25f, sB), 128.0f);
    }
  }

  // ---- phase 4: source_image pass-through (R10 placement) ----
  {
    const float4* s4 = (const float4*)src;
    float4*       d4 = (float4*)(out + NELEM);
    size_t base4 = (size_t)blk * 1536;
    #pragma unroll
    for (int i = 0; i < 6; ++i) {
      size_t f = base4 + i * 256 + tid;
      d4[f] = s4[f];
    }
  }
  __syncthreads();

  // ---- phase 3: upsample, -128, sgemm-FMA YCC->RGB, clip, *1/255, store ----
  float* oR = out + (size_t)(b * 3 + 0) * PLANE;
  float* oG = out + (size_t)(b * 3 + 1) * PLANE;
  float* oB = out + (size_t)(b * 3 + 2) * PLANE;
  #pragma unroll
  for (int i = 0; i < 2; ++i) {
    int g = tid + i * 256;           // 32 rows x 16 groups of 4 px
    int py = g >> 4, pxg = g & 15;
    int col = pxg * 4;
    int ybk = (py >> 3) * 8 + (col >> 3);
    int yoff = (py & 7) * 8 + (col & 7);
    float4 yv4 = *(const float4*)&Blk[ybk][yoff];
    float yv[4] = {yv4.x, yv4.y, yv4.z, yv4.w};

    int cy = py >> 1, cx = 2 * pxg;
    int cbk = 32 + (cy >> 3) * 4 + (cx >> 3);
    int coff = (cy & 7) * 8 + (cx & 7);
    float2 cbv = *(const float2*)&Blk[cbk][coff];
    float2 crv = *(const float2*)&Blk[cbk + 8][coff];
    float cb0 = __fadd_rn(cbv.x, -128.0f);
    float cb1 = __fadd_rn(cbv.y, -128.0f);
    float cr0 = __fadd_rn(crv.x, -128.0f);
    float cr1 = __fadd_rn(crv.y, -128.0f);
    float cb[4] = {cb0, cb0, cb1, cb1};
    float cr[4] = {cr0, cr0, cr1, cr1};

    float rr[4], gg[4], bb[4];
    #pragma unroll
    for (int j = 0; j < 4; ++j) {
      float R  = __fmaf_rn(cr[j], 1.402f, yv[j]);
      float G  = __fmaf_rn(cr[j], -0.714136f, __fmaf_rn(cb[j], -0.344136f, yv[j]));
      float Bv = __fmaf_rn(cb[j], 1.772f, yv[j]);
      R  = fminf(fmaxf(R,  0.0f), 255.0f);
      G  = fminf(fmaxf(G,  0.0f), 255.0f);
      Bv = fminf(fmaxf(Bv, 0.0f), 255.0f);
      rr[j] = __fmul_rn(R,  RCP255);   // post-round: mul ok (err <= 2e-6)
      gg[j] = __fmul_rn(G,  RCP255);
      bb[j] = __fmul_rn(Bv, RCP255);
    }
    size_t o = (size_t)(row0 + py) * WW + (col0 + col);
    *(float4*)(oR + o) = make_float4(rr[0], rr[1], rr[2], rr[3]);
    *(float4*)(oG + o) = make_float4(gg[0], gg[1], gg[2], gg[3]);
    *(float4*)(oB + o) = make_float4(bb[0], bb[1], bb[2], bb[3]);
  }
}

extern "C" void kernel_launch(void* const* d_in, const int* in_sizes, int n_in,
                              void* d_out, int out_size, void* d_ws, size_t ws_size,
                              hipStream_t stream) {
  (void)in_sizes; (void)n_in; (void)d_ws; (void)ws_size; (void)out_size;
  const float* x   = (const float*)d_in[0];
  const float* src = (const float*)d_in[1];
  float* out = (float*)d_out;

  diffjpeg_kernel<<<dim3(BATCH * 128), dim3(256), 0, stream>>>(x, src, out);
}